// Round 10
// baseline (325.159 us; speedup 1.0000x reference)
//
#include <hip/hip_runtime.h>

constexpr int B   = 2;
constexpr int T   = 2048;
constexpr int C   = 2048;
constexpr int H   = 32;
constexpr int HKV = 8;
constexpr int D   = 64;
constexpr float SCALE = 0.125f; // 1/sqrt(64)

typedef __attribute__((ext_vector_type(8))) short bf16x8;
typedef __attribute__((ext_vector_type(4))) float f32x4;

__device__ __forceinline__ unsigned short f2bf(float f) {
    unsigned u = __builtin_bit_cast(unsigned, f);
    u += 0x7fff + ((u >> 16) & 1);          // round-to-nearest-even
    return (unsigned short)(u >> 16);
}
__device__ __forceinline__ float bf2f(unsigned short u) {
    unsigned v = (unsigned)u << 16;
    return __builtin_bit_cast(float, v);
}
// pack two f32 -> two bf16 in one instruction (no builtin on gfx950)
__device__ __forceinline__ unsigned cvt_pk_bf16(float lo, float hi) {
    unsigned r;
    asm("v_cvt_pk_bf16_f32 %0, %1, %2" : "=v"(r) : "v"(lo), "v"(hi));
    return r;
}

typedef __attribute__((address_space(1))) const unsigned char ga_t;
typedef __attribute__((address_space(3))) unsigned char lds_t;
__device__ __forceinline__ void gl2lds16(const void* g, void* l) {
    // 16B per lane, dest = wave-uniform base + lane*16
    __builtin_amdgcn_global_load_lds((ga_t*)g, (lds_t*)l, 16, 0, 0);
}

// ---------------------------------------------------------------------------
// Fused fp32 -> bf16 cast of x + all 4 weights (outputs contiguous in ws).
// ---------------------------------------------------------------------------
__global__ __launch_bounds__(256) void cast_all_bf16(const float* __restrict__ x,
                                                     const float* __restrict__ wq,
                                                     const float* __restrict__ wk,
                                                     const float* __restrict__ wv,
                                                     const float* __restrict__ wc,
                                                     unsigned short* __restrict__ out) {
    const size_t b0 = (size_t)B * T * C;            // x end
    const size_t b1 = b0 + (size_t)H * D * C;       // Wq end
    const size_t b2 = b1 + (size_t)HKV * D * C;     // Wk end
    const size_t b3 = b2 + (size_t)HKV * D * C;     // Wv end
    size_t i = ((size_t)blockIdx.x * 256 + threadIdx.x) * 8;
    const float* src;
    size_t off;
    if (i < b0)      { src = x;  off = i; }
    else if (i < b1) { src = wq; off = i - b0; }
    else if (i < b2) { src = wk; off = i - b1; }
    else if (i < b3) { src = wv; off = i - b2; }
    else             { src = wc; off = i - b3; }
    float4 a = *(const float4*)(src + off);
    float4 b = *(const float4*)(src + off + 4);
    uint4 r;
    r.x = (unsigned)f2bf(a.x) | ((unsigned)f2bf(a.y) << 16);
    r.y = (unsigned)f2bf(a.z) | ((unsigned)f2bf(a.w) << 16);
    r.z = (unsigned)f2bf(b.x) | ((unsigned)f2bf(b.y) << 16);
    r.w = (unsigned)f2bf(b.z) | ((unsigned)f2bf(b.w) << 16);
    *(uint4*)(out + i) = r;
}

// ---------------------------------------------------------------------------
// bf16 MFMA NT GEMM — BK=64 (R8-proven): halved barrier count per K-element.
// LDS 32 KB, 8-chunk XOR swizzle via pre-swizzled global source.
// ---------------------------------------------------------------------------
template <typename OutT>
__device__ __forceinline__ void gemm_mfma_body(const unsigned short* __restrict__ Xh,
                                               const unsigned short* __restrict__ Wh,
                                               OutT* __restrict__ Y,
                                               int Nloc, int K, int bm, int bn) {
    __shared__ __align__(16) unsigned short As[128 * 64];
    __shared__ __align__(16) unsigned short Bs[128 * 64];
    char* AsB = (char*)As;
    char* BsB = (char*)Bs;

    const int tid  = threadIdx.x;
    const int wave = tid >> 6, lane = tid & 63;
    const int wm = (wave >> 1) * 64, wn = (wave & 1) * 64;
    const int m = lane & 15, quad = lane >> 4;

    // staging: thread t -> LDS slot t*16B (+ call*4KB); row r0 = t>>3 (+32/call),
    // chunk slot cs = t&7, source chunk cg = cs ^ (r0&7) (pre-swizzled global)
    const int r0 = tid >> 3;
    const int cs = tid & 7;
    const int cg = cs ^ (r0 & 7);
    const int ldst = tid * 16;

    const unsigned short* gA = Xh + (size_t)(bm + r0) * K + cg * 8;
    const unsigned short* gB = Wh + (size_t)(bn + r0) * K + cg * 8;
    const size_t rowStep32 = (size_t)32 * K;

    // frag LDS offsets: row ra, logical chunk kk*4+quad -> slot chunk ^ (ra&7)
    int aoff[4][2], boff[4][2];
#pragma unroll
    for (int mt = 0; mt < 4; ++mt)
#pragma unroll
        for (int kk = 0; kk < 2; ++kk) {
            int ra = wm + mt * 16 + m;
            aoff[mt][kk] = ra * 128 + ((((kk * 4 + quad) ^ (ra & 7))) << 4);
            int rb = wn + mt * 16 + m;
            boff[mt][kk] = rb * 128 + ((((kk * 4 + quad) ^ (rb & 7))) << 4);
        }

    f32x4 acc[4][4];
#pragma unroll
    for (int i = 0; i < 4; ++i)
#pragma unroll
        for (int j = 0; j < 4; ++j) acc[i][j] = (f32x4){0.f, 0.f, 0.f, 0.f};

    for (int k0 = 0; k0 < K; k0 += 64) {
        gl2lds16(gA,                 AsB + ldst);
        gl2lds16(gA +     rowStep32, AsB +  4096 + ldst);
        gl2lds16(gA + 2 * rowStep32, AsB +  8192 + ldst);
        gl2lds16(gA + 3 * rowStep32, AsB + 12288 + ldst);
        gl2lds16(gB,                 BsB + ldst);
        gl2lds16(gB +     rowStep32, BsB +  4096 + ldst);
        gl2lds16(gB + 2 * rowStep32, BsB +  8192 + ldst);
        gl2lds16(gB + 3 * rowStep32, BsB + 12288 + ldst);
        gA += 64;
        gB += 64;
        __syncthreads();

#pragma unroll
        for (int kk = 0; kk < 2; ++kk) {
            bf16x8 af[4], bfr[4];
#pragma unroll
            for (int mt = 0; mt < 4; ++mt) af[mt]  = *(const bf16x8*)(AsB + aoff[mt][kk]);
#pragma unroll
            for (int nt = 0; nt < 4; ++nt) bfr[nt] = *(const bf16x8*)(BsB + boff[nt][kk]);
#pragma unroll
            for (int mt = 0; mt < 4; ++mt)
#pragma unroll
                for (int nt = 0; nt < 4; ++nt)
                    acc[mt][nt] = __builtin_amdgcn_mfma_f32_16x16x32_bf16(af[mt], bfr[nt],
                                                                          acc[mt][nt], 0, 0, 0);
        }
        __syncthreads();
    }

#pragma unroll
    for (int mt = 0; mt < 4; ++mt)
#pragma unroll
        for (int r = 0; r < 4; ++r) {
            size_t row = (size_t)(bm + wm + mt * 16 + quad * 4 + r);
#pragma unroll
            for (int nt = 0; nt < 4; ++nt) {
                int col = bn + wn + nt * 16 + m;
                float v = acc[mt][nt][r];
                if constexpr (sizeof(OutT) == 2)
                    Y[row * Nloc + col] = f2bf(v);
                else
                    Y[row * Nloc + col] = v;
            }
        }
}

__global__ __launch_bounds__(256) void qkv_gemm_bf16(const unsigned short* __restrict__ Xh,
                                                     const unsigned short* __restrict__ Wqh,
                                                     const unsigned short* __restrict__ Wkh,
                                                     const unsigned short* __restrict__ Wvh,
                                                     unsigned short* __restrict__ qh,
                                                     unsigned short* __restrict__ kh,
                                                     unsigned short* __restrict__ vh) {
    int bn0 = blockIdx.x * 128;
    const unsigned short* Wsel;
    unsigned short* Ysel;
    int bnl, Nloc;
    if (bn0 < H * D)                { Wsel = Wqh; Ysel = qh; bnl = bn0;                  Nloc = H * D;   }
    else if (bn0 < H*D + HKV*D)     { Wsel = Wkh; Ysel = kh; bnl = bn0 - H * D;          Nloc = HKV * D; }
    else                            { Wsel = Wvh; Ysel = vh; bnl = bn0 - H*D - HKV*D;    Nloc = HKV * D; }
    gemm_mfma_body<unsigned short>(Xh, Wsel, Ysel, Nloc, C, blockIdx.y * 128, bnl);
}

__global__ __launch_bounds__(256) void out_gemm_bf16(const unsigned short* __restrict__ Xh,
                                                     const unsigned short* __restrict__ Wh,
                                                     float* __restrict__ Y) {
    gemm_mfma_body<float>(Xh, Wh, Y, C, C, blockIdx.y * 128, blockIdx.x * 128);
}

// ---------------------------------------------------------------------------
// Fused RoPE in-place on bf16 q and k (q gets softmax scale * log2e folded in)
// ---------------------------------------------------------------------------
__global__ void rope_fused(unsigned short* __restrict__ qh, unsigned short* __restrict__ kh,
                           const int* __restrict__ pos_ids, float qscale) {
    int idx = blockIdx.x * blockDim.x + threadIdx.x;
    const int qtotal = B * T * H * 32;
    unsigned short* buf;
    int nheads, rel;
    float sc;
    if (idx < qtotal) { buf = qh; nheads = H;   sc = qscale; rel = idx; }
    else              { buf = kh; nheads = HKV; sc = 1.0f;   rel = idx - qtotal; }
    int d = rel & 31;
    int rest = rel >> 5;                 // = (b*T + t)*nheads + h
    int t = (rest / nheads) % T;
    float pos = (float)pos_ids[t];
    int i1 = d >> 1;
    const float NEG_LF = -(2.0f / 64.0f) * 13.287712379549449f; // -2/D * log2(10000)
    float a1 = pos * exp2f(NEG_LF * (float)i1);
    float a2 = pos * exp2f(NEG_LF * (float)(i1 + 16));
    float c1 = cosf(a1), s1 = sinf(a1);
    float c2 = cosf(a2), s2 = sinf(a2);
    size_t base = (size_t)rest * D + d;
    float x1 = bf2f(buf[base]), x2 = bf2f(buf[base + 32]);
    buf[base]      = f2bf((x1 * c1 - x2 * s1) * sc);
    buf[base + 32] = f2bf((x2 * c2 + x1 * s2) * sc);
}

// ---------------------------------------------------------------------------
// V transpose bf16 [b][t][hkv][d] -> [b][hkv][d][t]
// ---------------------------------------------------------------------------
__global__ __launch_bounds__(256) void v_transpose(const unsigned short* __restrict__ vh,
                                                   unsigned short* __restrict__ vtg) {
    __shared__ unsigned short Vs[64][72];
    const int t0 = blockIdx.x * 64;
    const int hkv = blockIdx.y;
    const int b = blockIdx.z;
    const int tid = threadIdx.x;

    for (int e = tid; e < 512; e += 256) {
        int t = e >> 3, d8 = (e & 7) * 8;
        uint4 val = *(const uint4*)(vh + ((size_t)((b * T + t0 + t) * HKV) + hkv) * D + d8);
        unsigned short tmp[8];
        *(uint4*)tmp = val;
#pragma unroll
        for (int i = 0; i < 8; ++i) Vs[d8 + i][t] = tmp[i];
    }
    __syncthreads();
    for (int e = tid; e < 512; e += 256) {
        int d = e >> 3, c = e & 7;
        *(uint4*)(vtg + ((size_t)((b * HKV + hkv) * D) + d) * T + t0 + c * 8) =
            *(const uint4*)&Vs[d][c * 8];
    }
}

// ---------------------------------------------------------------------------
// bf16 MFMA flash attention v13: triangle-folded R8 core (single-buffered
// gl2lds staging — R9's dbuf was neutral-to-negative, reverted) with P in a
// SEPARATE wave-private 8 KB strip instead of aliased into Ks:
//   P write->read is wave-private (in-wave lgkm ordering only), so the mid
//   __syncthreads that protected the Ks alias WAR is DELETED. Barriers per
//   iteration: 3 -> 2. LDS 16.4 -> 24.6 KB (grid is 4 blocks/CU; anything
//   <= 40 KB keeps full residency, so the alias's LDS saving bought nothing).
// ---------------------------------------------------------------------------
__global__ __launch_bounds__(256, 4) void flash_attn_mfma(const unsigned short* __restrict__ Qh,
                                                          const unsigned short* __restrict__ Kh,
                                                          const unsigned short* __restrict__ Vtg,
                                                          unsigned short* __restrict__ Yh) {
    __shared__ __align__(16) unsigned short Ks[64 * 64];   // [key][d], XOR-swizzled chunks
    __shared__ __align__(16) unsigned short Vt[64 * 64];   // [d][key], XOR-swizzled chunks
    __shared__ __align__(16) unsigned short Ps[4 * 16 * 64]; // wave-private P strips (swizzled)

    const int pairi = blockIdx.x;          // 0 .. T/128-1
    const int h  = blockIdx.y;
    const int b  = blockIdx.z;
    const int hkv = h >> 2;
    const int tid = threadIdx.x;
    const int wave = tid >> 6;
    const int lane = tid & 63;
    const int m = lane & 15;
    const int quad = lane >> 4;

    // staging: thread t -> LDS slot t*16B (row r0=t>>3, chunk cs=t&7),
    // source chunk cg = cs ^ (r0&7)  (XOR applied on the global address)
    const int r0 = tid >> 3, cs = tid & 7, cg = cs ^ (r0 & 7);
    const int wbase = (tid & 192) * 16;
    char* KsB = (char*)Ks;
    char* VtB = (char*)Vt;
    char* PsB = (char*)Ps;

    // P-strip addressing (wave-private 2KB quadrant of Ps):
    //   plain byte of key k, query m  =  m*128 + k*2 ; chunk-XOR swizzle ^ (m&7)
    const int m7 = m & 7;
    const int pwr = wave * 2048 + m * 128 + ((quad & 1) * 8);  // write base (+chunk sel per nt)
    const int qh2 = quad >> 1;
    const int prd = wave * 2048 + m * 128;                      // read base

    const unsigned short* gKbase = Kh + ((size_t)(b * T) * HKV + hkv) * D
                                      + (size_t)r0 * (HKV * D) + cg * 8;
    const unsigned short* gVbase = Vtg + ((size_t)(b * HKV + hkv) * D) * (size_t)T
                                       + (size_t)r0 * T + cg * 8;

#pragma unroll 1
    for (int half = 0; half < 2; ++half) {
        const int qt = half ? pairi : (T / 64 - 1 - pairi);   // heavy tile, then light tile
        const int q0 = qt * 64;
        const int qmin = q0 + wave * 16;

        // Q B-frags: this wave's 16 queries q0 + wave*16 + m
        const unsigned short* qrow = Qh + ((size_t)((b * T + q0 + wave * 16 + m) * H) + h) * D;
        const bf16x8 qa0 = *(const bf16x8*)(qrow + quad * 8);
        const bf16x8 qa1 = *(const bf16x8*)(qrow + 32 + quad * 8);

        f32x4 o[4];
#pragma unroll
        for (int dt = 0; dt < 4; ++dt) o[dt] = (f32x4){0.f, 0.f, 0.f, 0.f};
        float ms = -1e30f, ls = 0.f;

        const unsigned short* gK = gKbase;
        const unsigned short* gV = gVbase;

        for (int k0 = 0; k0 <= q0; k0 += 64) {
            gl2lds16(gK,                          KsB + wbase);
            gl2lds16(gK + (size_t)32 * (HKV * D), KsB + 4096 + wbase);
            gl2lds16(gV,                          VtB + wbase);
            gl2lds16(gV + (size_t)32 * T,         VtB + 4096 + wbase);
            gK += (size_t)64 * (HKV * D);
            gV += 64;
            __syncthreads();

            // ---- S^T = K · Q^T  (4 key-tiles of 16) ----
            f32x4 s[4];
            __builtin_amdgcn_s_setprio(1);
#pragma unroll
            for (int nt = 0; nt < 4; ++nt) {
                const int kmin = k0 + nt * 16;
                if (kmin > qmin + 15) {            // fully masked tile
                    s[nt] = (f32x4){-1e30f, -1e30f, -1e30f, -1e30f};
                    continue;
                }
                int row = nt * 16 + m;
                const bf16x8 ka0 = *(const bf16x8*)(KsB + row * 128 + ((quad ^ (m & 7)) * 16));
                const bf16x8 ka1 = *(const bf16x8*)(KsB + row * 128 + (((quad + 4) ^ (m & 7)) * 16));
                f32x4 acc = (f32x4){0.f, 0.f, 0.f, 0.f};
                acc = __builtin_amdgcn_mfma_f32_16x16x32_bf16(ka0, qa0, acc, 0, 0, 0);
                acc = __builtin_amdgcn_mfma_f32_16x16x32_bf16(ka1, qa1, acc, 0, 0, 0);
                if (kmin + 15 > qmin) {            // diagonal: elementwise mask
                    int c0 = qmin - kmin + m - 4 * quad;   // mask if r > c0
#pragma unroll
                    for (int r = 0; r < 4; ++r)
                        if (r > c0) acc[r] = -1e30f;
                }
                s[nt] = acc;
            }
            __builtin_amdgcn_s_setprio(0);

            // ---- base-2 online softmax (lane owns query m; reduce across quads) ----
            float mx = s[0][0];
#pragma unroll
            for (int nt = 0; nt < 4; ++nt)
#pragma unroll
                for (int r = 0; r < 4; ++r) mx = fmaxf(mx, s[nt][r]);
            mx = fmaxf(mx, __shfl_xor(mx, 16));
            mx = fmaxf(mx, __shfl_xor(mx, 32));

            // defer-rescale: only pay alpha broadcast + O rescale when the running
            // max grew by more than THR (P values stay bounded by 2^THR = 256)
            float al = 1.0f;
            if (__any(mx > ms + 8.0f)) {
                float mnew = fmaxf(ms, mx);
                al = exp2f(ms - mnew);
                ms = mnew;
                float av[4];
#pragma unroll
                for (int r = 0; r < 4; ++r)
                    av[r] = __shfl(al, quad * 20 + r);   // lane with m' = quad*4+r
#pragma unroll
                for (int dt = 0; dt < 4; ++dt)
#pragma unroll
                    for (int r = 0; r < 4; ++r) o[dt][r] *= av[r];
            }

            float psum = 0.f;
#pragma unroll
            for (int nt = 0; nt < 4; ++nt) {
                float p0 = exp2f(s[nt][0] - ms);
                float p1 = exp2f(s[nt][1] - ms);
                float p2 = exp2f(s[nt][2] - ms);
                float p3 = exp2f(s[nt][3] - ms);
                psum += (p0 + p1) + (p2 + p3);
                uint2 w;
                w.x = cvt_pk_bf16(p0, p1);
                w.y = cvt_pk_bf16(p2, p3);
                // keys nt*16+quad*4..+3 of query m, chunk-XOR swizzled (wave-private)
                *(uint2*)(PsB + pwr + (((2 * nt + qh2) ^ m7) << 4)) = w;
            }
            psum += __shfl_xor(psum, 16);
            psum += __shfl_xor(psum, 32);
            ls = ls * al + psum;

            // ---- O += P · V  (P strip is wave-private: no barrier needed) ----
            const bf16x8 pa0 = *(const bf16x8*)(PsB + prd + ((quad ^ m7) << 4));
            const bf16x8 pa1 = *(const bf16x8*)(PsB + prd + (((quad + 4) ^ m7) << 4));
            __builtin_amdgcn_s_setprio(1);
#pragma unroll
            for (int dt = 0; dt < 4; ++dt) {
                int vrow = dt * 16 + m;
                const bf16x8 vb0 = *(const bf16x8*)(VtB + vrow * 128 + ((quad ^ (m & 7)) * 16));
                const bf16x8 vb1 = *(const bf16x8*)(VtB + vrow * 128 + (((quad + 4) ^ (m & 7)) * 16));
                o[dt] = __builtin_amdgcn_mfma_f32_16x16x32_bf16(pa0, vb0, o[dt], 0, 0, 0);
                o[dt] = __builtin_amdgcn_mfma_f32_16x16x32_bf16(pa1, vb1, o[dt], 0, 0, 0);
            }
            __builtin_amdgcn_s_setprio(0);
            __syncthreads();   // protect Ks/Vt before restage
        }

        // ---- epilogue: O / l -> bf16 y[b][t][h][d] ----
#pragma unroll
        for (int r = 0; r < 4; ++r) {
            float lv = __shfl(ls, quad * 20 + r);
            float inv = 1.0f / lv;
            int trow = q0 + wave * 16 + quad * 4 + r;
            unsigned short* yp = Yh + ((size_t)(b * T + trow) * H + h) * D;
#pragma unroll
            for (int dt = 0; dt < 4; ++dt)
                yp[dt * 16 + m] = f2bf(o[dt][r] * inv);
        }
    }
}

// ---------------------------------------------------------------------------
extern "C" void kernel_launch(void* const* d_in, const int* in_sizes, int n_in,
                              void* d_out, int out_size, void* d_ws, size_t ws_size,
                              hipStream_t stream) {
    const float* x  = (const float*)d_in[0];
    const float* Wq = (const float*)d_in[1];
    const float* Wk = (const float*)d_in[2];
    const float* Wv = (const float*)d_in[3];
    const float* Wc = (const float*)d_in[4];
    const int*  pos = (const int*)d_in[5];
    float* out = (float*)d_out;

    unsigned short* xh  = (unsigned short*)d_ws;           // contiguous with the 4 weight
    unsigned short* wqh = xh  + (size_t)B * T * C;         // buffers — fused cast relies on it
    unsigned short* wkh = wqh + (size_t)H * D * C;
    unsigned short* wvh = wkh + (size_t)HKV * D * C;
    unsigned short* wch = wvh + (size_t)HKV * D * C;
    unsigned short* qh  = wch + (size_t)C * C;
    unsigned short* kh  = qh  + (size_t)B * T * H * D;
    unsigned short* vh  = kh  + (size_t)B * T * HKV * D;
    unsigned short* vtg = vh  + (size_t)B * T * HKV * D;
    unsigned short* yh  = xh;                              // alias (xh dead after QKV)

    // 1) fused cast fp32 -> bf16 of x + Wq + Wk + Wv + Wc (one launch)
    const size_t cast_total = (size_t)B * T * C + (size_t)(H + 2 * HKV) * D * C + (size_t)C * C;
    cast_all_bf16<<<(unsigned)(cast_total / (256 * 8)), 256, 0, stream>>>(x, Wq, Wk, Wv, Wc, xh);

    // 2) fused QKV projection (bf16 MFMA, BK=64)
    dim3 g1((H * D + 2 * HKV * D) / 128, (B * T) / 128);
    qkv_gemm_bf16<<<g1, 256, 0, stream>>>(xh, wqh, wkh, wvh, qh, kh, vh);

    // 3) fused RoPE on q (scale folded) + k; V transpose
    const float QSCALE = SCALE * 1.4426950408889634f;  // SCALE * log2(e)
    rope_fused<<<(B * T * (H + HKV) * 32) / 256, 256, 0, stream>>>(qh, kh, pos, QSCALE);
    v_transpose<<<dim3(T / 64, HKV, B), 256, 0, stream>>>(vh, vtg);

    // 4) causal GQA flash attention (triangle-folded: 1024 uniform blocks)
    dim3 g2(T / 128, H, B);
    flash_attn_mfma<<<g2, 256, 0, stream>>>(qh, kh, vtg, yh);

    // 5) output projection (BK=64)
    dim3 g3(C / 128, (B * T) / 128);
    out_gemm_bf16<<<g3, 256, 0, stream>>>(yh, wch, out);
}